// Round 7
// baseline (1506.525 us; speedup 1.0000x reference)
//
#include <hip/hip_runtime.h>
#include <hip/hip_bf16.h>

#define HID 128
#define SEQ 512
#define INS 14
#define BC 16
// K0 = 160 : [x(14) | 1 | pad->32 | h0(128)]   -> 5 k-steps of 32
// K1 = 256 : [h0(128) | h1(128)]               -> 8 k-steps of 32
#define X0STRIDE 168  // 160 + 8 pad shorts
#define X1STRIDE 264  // 256 + 8 pad shorts
#define NFRAG0 10240          // 8 unit-groups * 4 gates * 5 ksteps * 64 lanes
#define NFRAG1 16384          // 8 unit-groups * 4 gates * 8 ksteps * 64 lanes
#define W1BASE (NFRAG0 * 8)   // short offset of W1 region in ws

typedef __attribute__((ext_vector_type(8))) short bs8;
typedef __attribute__((ext_vector_type(4))) float f4;

__device__ __forceinline__ short f2bf(float f) {
    union { float f; unsigned u; } a; a.f = f;
    unsigned u = a.u;
    u += 0x7fffu + ((u >> 16) & 1u);   // RNE
    return (short)(u >> 16);
}
__device__ __forceinline__ float bf2f(short s) {
    union { unsigned u; float f; } a;
    a.u = ((unsigned)(unsigned short)s) << 16;
    return a.f;
}
__device__ __forceinline__ float sigm(float x) {
    return __builtin_amdgcn_rcpf(1.f + __builtin_amdgcn_exp2f(x * -1.44269504f));
}
__device__ __forceinline__ float tanh_(float x) {
    return __builtin_fmaf(2.f, __builtin_amdgcn_rcpf(1.f + __builtin_amdgcn_exp2f(x * -2.88539008f)), -1.f);
}

// ---------------------------------------------------------------------------
// prep: swizzle weights into MFMA B-fragment order in ws (bf16 bits).
// Layout identical to rounds 4-6 (indexed by old 8-way unit-group id).
// ---------------------------------------------------------------------------
__global__ void lstm_prep(
    const float* __restrict__ Wih0, const float* __restrict__ Whh0,
    const float* __restrict__ bih0, const float* __restrict__ bhh0,
    const float* __restrict__ Wih1, const float* __restrict__ Whh1,
    short* __restrict__ wsw)
{
    int f = blockIdx.x * 256 + threadIdx.x;
    if (f >= NFRAG0 + NFRAG1) return;
    if (f < NFRAG0) {
        int lane = f & 63, t = f >> 6;
        int ks = t % 5, gw = t / 5, g = gw & 3, wv = gw >> 2;
        int row = g * HID + wv * 16 + (lane & 15);
        int kbase = ks * 32 + (lane >> 4) * 8;
        for (int j = 0; j < 8; ++j) {
            int k = kbase + j;
            float v;
            if (k < INS)        v = Wih0[row * INS + k];
            else if (k == INS)  v = bih0[row] + bhh0[row];
            else if (k < 32)    v = 0.f;
            else                v = Whh0[row * HID + (k - 32)];
            wsw[f * 8 + j] = f2bf(v);
        }
    } else {
        int fl = f - NFRAG0;
        int lane = fl & 63, t = fl >> 6;
        int ks = t & 7, g = (t >> 3) & 3, wv = t >> 5;
        int row = g * HID + wv * 16 + (lane & 15);
        int kbase = ks * 32 + (lane >> 4) * 8;
        for (int j = 0; j < 8; ++j) {
            int k = kbase + j;
            float v = (k < HID) ? Wih1[row * HID + k] : Whh1[row * HID + (k - HID)];
            wsw[f * 8 + j] = f2bf(v);
        }
    }
}

// ---------------------------------------------------------------------------
// main. Rounds 2-6 lesson: at 8 waves/block the allocator hard-splits the
// 256-reg budget into 128 arch + 128 accum and refuses to keep 208 weight
// regs resident -> weights stream from L2 every step (416 KB/CU/step at
// ~66 B/cyc/CU = the 6280-cyc step = the 1350 us plateau). This round:
// 4 waves/block, 1 wave/SIMD (waves_per_eu(1,1)) -> 512-reg budget/wave
// (256 arch + 256 accum). Each wave owns 32 units (2 n-tiles of 16).
// W1 frags (exactly 256 regs) pinned into AGPRs ("+a") — gfx950 MFMA reads
// B directly from AGPR. W0 frags (160 regs) pinned "+v" in the arch half;
// working set ~70 regs also arch. n-tiles processed sequentially so acc
// stays at 16 regs.
// ---------------------------------------------------------------------------
__global__ __attribute__((amdgpu_flat_work_group_size(256, 256)))
__attribute__((amdgpu_waves_per_eu(1, 1))) void lstm_fused(
    const float* __restrict__ x,
    const float* __restrict__ Wfc,  const float* __restrict__ bfc,
    const float* __restrict__ bih1, const float* __restrict__ bhh1,
    const short* __restrict__ wsw,
    float* __restrict__ out)
{
    __shared__ __align__(16) short xh0[2][BC][X0STRIDE];
    __shared__ __align__(16) short xh1[2][BC][X1STRIDE];

    const int tid  = threadIdx.x;
    const int lane = tid & 63;
    const int wv   = tid >> 6;        // 0..3
    const int col  = lane & 15;
    const int quad = lane >> 4;
    const int un0  = wv * 32 + col;       // n-tile 0 unit
    const int un1  = wv * 32 + 16 + col;  // n-tile 1 unit
    const int b0   = blockIdx.x * BC;

    // ---- weight fragment bases (old 8-way group id = wv*2 + ntile) ----
    const short* wb0_0 = wsw + (((wv * 2 + 0) * 20) * 64 + lane) * 8;
    const short* wb0_1 = wsw + (((wv * 2 + 1) * 20) * 64 + lane) * 8;
    const short* wb1_0 = wsw + W1BASE + (((wv * 2 + 0) * 32) * 64 + lane) * 8;
    const short* wb1_1 = wsw + W1BASE + (((wv * 2 + 1) * 32) * 64 + lane) * 8;

#define DW0(n,g,ks) bs8 w0_##n##_##g##_##ks = *(const bs8*)(wb0_##n + ((g)*5+(ks))*512); \
                    asm volatile("" : "+v"(w0_##n##_##g##_##ks));
#define DW1(n,g,ks) bs8 w1_##n##_##g##_##ks = *(const bs8*)(wb1_##n + ((g)*8+(ks))*512); \
                    asm volatile("" : "+a"(w1_##n##_##g##_##ks));
#define DW0G(n,g) DW0(n,g,0) DW0(n,g,1) DW0(n,g,2) DW0(n,g,3) DW0(n,g,4)
#define DW1G(n,g) DW1(n,g,0) DW1(n,g,1) DW1(n,g,2) DW1(n,g,3) DW1(n,g,4) DW1(n,g,5) DW1(n,g,6) DW1(n,g,7)
    DW0G(0,0) DW0G(0,1) DW0G(0,2) DW0G(0,3)
    DW0G(1,0) DW0G(1,1) DW0G(1,2) DW0G(1,3)
    DW1G(0,0) DW1G(0,1) DW1G(0,2) DW1G(0,3)
    DW1G(1,0) DW1G(1,1) DW1G(1,2) DW1G(1,3)

    const float b1_0_0 = bih1[0 * HID + un0] + bhh1[0 * HID + un0];
    const float b1_0_1 = bih1[1 * HID + un0] + bhh1[1 * HID + un0];
    const float b1_0_2 = bih1[2 * HID + un0] + bhh1[2 * HID + un0];
    const float b1_0_3 = bih1[3 * HID + un0] + bhh1[3 * HID + un0];
    const float b1_1_0 = bih1[0 * HID + un1] + bhh1[0 * HID + un1];
    const float b1_1_1 = bih1[1 * HID + un1] + bhh1[1 * HID + un1];
    const float b1_1_2 = bih1[2 * HID + un1] + bhh1[2 * HID + un1];
    const float b1_1_3 = bih1[3 * HID + un1] + bhh1[3 * HID + un1];

    // ---- LDS init: zeros + constant-1 bias column ----
    for (int idx = tid; idx < 2 * BC * X0STRIDE; idx += 256) ((short*)xh0)[idx] = 0;
    for (int idx = tid; idx < 2 * BC * X1STRIDE; idx += 256) ((short*)xh1)[idx] = 0;
    __syncthreads();
    if (tid < 2 * BC) xh0[tid >> 4][tid & 15][INS] = (short)0x3f80;  // 1.0 bf16

    // ---- x(t) staging: one float per thread, prefetched one step ahead ----
    const bool xldr = (tid < BC * INS);          // 224 of 256 threads
    const int  xm = tid / INS;
    const int  xi = tid - xm * INS;
    const float* xp = xldr ? (x + ((size_t)(b0 + xm) * SEQ) * INS + xi) : x;
    float xv = xldr ? xp[0] : 0.f;

    float c0_0_0 = 0.f, c0_0_1 = 0.f, c0_0_2 = 0.f, c0_0_3 = 0.f;
    float c0_1_0 = 0.f, c0_1_1 = 0.f, c0_1_2 = 0.f, c0_1_3 = 0.f;
    float c1_0_0 = 0.f, c1_0_1 = 0.f, c1_0_2 = 0.f, c1_0_3 = 0.f;
    float c1_1_0 = 0.f, c1_1_1 = 0.f, c1_1_2 = 0.f, c1_1_3 = 0.f;
    const int aoff = quad * 8;

    for (int t = 0; t < SEQ; ++t) {
        const int p = t & 1, q = p ^ 1;
        if (xldr) xh0[p][xm][xi] = f2bf(xv);
        float xnext = (xldr && (t + 1 < SEQ)) ? xp[(t + 1) * INS] : 0.f;
        __syncthreads();  // x(t) + h0(t-1) + h1(t-1) visible

#define L0S(n,ks) { const bs8 af = *(const bs8*)&xh0[p][col][(ks)*32 + aoff]; \
        acc_0 = __builtin_amdgcn_mfma_f32_16x16x32_bf16(af, w0_##n##_0_##ks, acc_0, 0,0,0); \
        acc_1 = __builtin_amdgcn_mfma_f32_16x16x32_bf16(af, w0_##n##_1_##ks, acc_1, 0,0,0); \
        acc_2 = __builtin_amdgcn_mfma_f32_16x16x32_bf16(af, w0_##n##_2_##ks, acc_2, 0,0,0); \
        acc_3 = __builtin_amdgcn_mfma_f32_16x16x32_bf16(af, w0_##n##_3_##ks, acc_3, 0,0,0); }
#define CELL0(n,r) { \
        float ig = sigm(acc_0[r]); \
        float fg = sigm(acc_1[r]); \
        float gg = tanh_(acc_2[r]); \
        float og = sigm(acc_3[r]); \
        c0_##n##_##r = __builtin_fmaf(fg, c0_##n##_##r, ig * gg); \
        float h = og * tanh_(c0_##n##_##r); \
        short hb = f2bf(h); \
        xh0[q][quad * 4 + r][32 + un##n] = hb; \
        xh1[p][quad * 4 + r][un##n]      = hb; }
#define NT0(n) { \
        f4 acc_0 = {0.f,0.f,0.f,0.f}, acc_1 = {0.f,0.f,0.f,0.f}; \
        f4 acc_2 = {0.f,0.f,0.f,0.f}, acc_3 = {0.f,0.f,0.f,0.f}; \
        L0S(n,0) L0S(n,1) L0S(n,2) L0S(n,3) L0S(n,4) \
        CELL0(n,0) CELL0(n,1) CELL0(n,2) CELL0(n,3) }

        NT0(0) NT0(1)
        __syncthreads();  // h0(t) visible for layer 1

#define L1S(n,ks) { const bs8 af = *(const bs8*)&xh1[p][col][(ks)*32 + aoff]; \
        acc_0 = __builtin_amdgcn_mfma_f32_16x16x32_bf16(af, w1_##n##_0_##ks, acc_0, 0,0,0); \
        acc_1 = __builtin_amdgcn_mfma_f32_16x16x32_bf16(af, w1_##n##_1_##ks, acc_1, 0,0,0); \
        acc_2 = __builtin_amdgcn_mfma_f32_16x16x32_bf16(af, w1_##n##_2_##ks, acc_2, 0,0,0); \
        acc_3 = __builtin_amdgcn_mfma_f32_16x16x32_bf16(af, w1_##n##_3_##ks, acc_3, 0,0,0); }
#define CELL1(n,r) { \
        float ig = sigm(acc_0[r]); \
        float fg = sigm(acc_1[r]); \
        float gg = tanh_(acc_2[r]); \
        float og = sigm(acc_3[r]); \
        c1_##n##_##r = __builtin_fmaf(fg, c1_##n##_##r, ig * gg); \
        float h = og * tanh_(c1_##n##_##r); \
        xh1[q][quad * 4 + r][HID + un##n] = f2bf(h); }
#define NT1(n) { \
        f4 acc_0 = {b1_##n##_0, b1_##n##_0, b1_##n##_0, b1_##n##_0}; \
        f4 acc_1 = {b1_##n##_1, b1_##n##_1, b1_##n##_1, b1_##n##_1}; \
        f4 acc_2 = {b1_##n##_2, b1_##n##_2, b1_##n##_2, b1_##n##_2}; \
        f4 acc_3 = {b1_##n##_3, b1_##n##_3, b1_##n##_3, b1_##n##_3}; \
        L1S(n,0) L1S(n,1) L1S(n,2) L1S(n,3) L1S(n,4) L1S(n,5) L1S(n,6) L1S(n,7) \
        CELL1(n,0) CELL1(n,1) CELL1(n,2) CELL1(n,3) }

        NT1(0) NT1(1)

        xv = xnext;
        // loop-top barrier doubles as the post-cell1 barrier
    }
    __syncthreads();

    // ---- final FC (128 -> 1) + sigmoid; h1(T-1) in xh1[0][.][HID+..] ----
    if (tid < BC) {
        float s = bfc[0];
#pragma unroll 8
        for (int k2 = 0; k2 < HID; ++k2)
            s += bf2f(xh1[0][tid][HID + k2]) * Wfc[k2];
        out[b0 + tid] = sigm(s);
    }
}

extern "C" void kernel_launch(void* const* d_in, const int* in_sizes, int n_in,
                              void* d_out, int out_size, void* d_ws, size_t ws_size,
                              hipStream_t stream) {
    const float* x    = (const float*)d_in[0];
    const float* Wih0 = (const float*)d_in[1];
    const float* Whh0 = (const float*)d_in[2];
    const float* bih0 = (const float*)d_in[3];
    const float* bhh0 = (const float*)d_in[4];
    const float* Wih1 = (const float*)d_in[5];
    const float* Whh1 = (const float*)d_in[6];
    const float* bih1 = (const float*)d_in[7];
    const float* bhh1 = (const float*)d_in[8];
    const float* Wfc  = (const float*)d_in[9];
    const float* bfc  = (const float*)d_in[10];
    float* out = (float*)d_out;
    short* wsw = (short*)d_ws;   // 426 KB of bf16 fragment-ordered weights

    int nfrag = NFRAG0 + NFRAG1;
    lstm_prep<<<(nfrag + 255) / 256, 256, 0, stream>>>(Wih0, Whh0, bih0, bhh0,
                                                       Wih1, Whh1, wsw);
    dim3 grid(2048 / BC);   // 128 blocks, 1 per CU
    dim3 block(256);        // 4 waves, 1/SIMD; each wave owns 32 hidden units
    lstm_fused<<<grid, block, 0, stream>>>(x, Wfc, bfc, bih1, bhh1, wsw, out);
}